// Round 1
// baseline (283.720 us; speedup 1.0000x reference)
//
#include <hip/hip_runtime.h>
#include <math.h>

#define NBATCH 32
#define NL     4096
#define NC     8
#define NT     64
#define NTOT   (NBATCH * NL * NC)   // 1,048,576 delta elements

// ---------------------------------------------------------------------------
// Kernel 1: fp64 sum / sumsq of delta over all B*L*C elements.
// delta[b,l,c] = (l==0) ? 0 : in[b,l,c] - in[b,l-1,c], layout [B,L,C].
// Flat i = (b*L + l)*C + c  =>  l==0  <=>  (i mod (L*C)) < C.
// 256 blocks x 256 threads, 16 elems/thread, coalesced.
// ---------------------------------------------------------------------------
__global__ __launch_bounds__(256) void reduce_kernel(const float* __restrict__ in,
                                                     double* __restrict__ part) {
    __shared__ double sm[256], sm2[256];
    const int tid = threadIdx.x;
    double s = 0.0, s2 = 0.0;
    for (int i = blockIdx.x * 256 + tid; i < NTOT; i += 256 * 256) {
        double d = 0.0;
        if ((i & (NL * NC - 1)) >= NC) {
            d = (double)in[i] - (double)in[i - NC];
        }
        s  += d;
        s2 += d * d;
    }
    sm[tid] = s; sm2[tid] = s2;
    __syncthreads();
    for (int off = 128; off > 0; off >>= 1) {
        if (tid < off) { sm[tid] += sm[tid + off]; sm2[tid] += sm2[tid + off]; }
        __syncthreads();
    }
    if (tid == 0) {
        part[2 * blockIdx.x]     = sm[0];
        part[2 * blockIdx.x + 1] = sm2[0];
    }
}

// ---------------------------------------------------------------------------
// Kernel 2: reduce 256 partials -> mean/var -> fold BN into A, Bc:
//   d_norm = (delta - mean) * rsqrt(var+eps) * gamma + beta = delta*A + Bc
// ---------------------------------------------------------------------------
__global__ __launch_bounds__(256) void finalize_kernel(const double* __restrict__ part,
                                                       const float* __restrict__ gamma,
                                                       const float* __restrict__ beta,
                                                       double* __restrict__ coef) {
    __shared__ double sm[256], sm2[256];
    const int tid = threadIdx.x;
    sm[tid]  = part[2 * tid];
    sm2[tid] = part[2 * tid + 1];
    __syncthreads();
    for (int off = 128; off > 0; off >>= 1) {
        if (tid < off) { sm[tid] += sm[tid + off]; sm2[tid] += sm2[tid + off]; }
        __syncthreads();
    }
    if (tid == 0) {
        const double mean = sm[0] / (double)NTOT;
        const double var  = sm2[0] / (double)NTOT - mean * mean;
        const double inv  = 1.0 / sqrt(var + 1e-5);
        const double A    = inv * (double)gamma[0];
        const double Bc   = (double)beta[0] - mean * A;
        coef[0] = A;
        coef[1] = Bc;
    }
}

// ---------------------------------------------------------------------------
// Kernel 3: LIF over T=64 steps. One thread owns 4 consecutive l-neurons.
//   enc_t = d * w[t] + b[t]
//   v    += (enc_t - v) * 0.5        (TAU = 2)
//   s     = (v >= 1.0)               (V_TH = 1; hard reset v=0 on spike)
// Output [B,T,C,L]: out[((b*T+t)*C+c)*L + l] -- float4 store per t, l fastest
// => 64 lanes x 16 B = 1 KB contiguous per wave per store instruction.
// Entire value path in fp64 to match an fp64 reference bit-for-bit on the
// binary spike decisions.
// ---------------------------------------------------------------------------
__global__ __launch_bounds__(256) void lif_kernel(const float* __restrict__ in,
                                                  const float* __restrict__ wv,
                                                  const float* __restrict__ bv,
                                                  const double* __restrict__ coef,
                                                  float* __restrict__ out) {
    __shared__ double sw[NT], sb[NT];
    const int tid = threadIdx.x;
    if (tid < NT) { sw[tid] = (double)wv[tid]; sb[tid] = (double)bv[tid]; }
    __syncthreads();

    const double A  = coef[0];
    const double Bc = coef[1];

    const int blk   = blockIdx.x;      // 0..1023 = B(32) * C(8) * (L/1024)(4)
    const int chunk = blk & 3;
    const int bc    = blk >> 2;
    const int c     = bc & 7;
    const int b     = bc >> 3;
    const int l     = chunk * 1024 + tid * 4;

    const float* base = in + (b * NL + l) * NC + c;

    double d[4];
#pragma unroll
    for (int k = 0; k < 4; k++) {
        if (l + k == 0) {
            d[k] = Bc;                          // delta == 0 at l==0
        } else {
            const double cur = (double)base[k * NC];
            const double prv = (double)base[(k - 1) * NC];
            d[k] = (cur - prv) * A + Bc;
        }
    }

    double v[4] = {0.0, 0.0, 0.0, 0.0};
    float* obase = out + ((b * NT) * NC + c) * NL + l;

#pragma unroll 4
    for (int t = 0; t < NT; t++) {
        const double wt = sw[t];
        const double bt = sb[t];
        float r[4];
#pragma unroll
        for (int k = 0; k < 4; k++) {
            const double x = d[k] * wt + bt;
            v[k] = v[k] + (x - v[k]) * 0.5;
            const bool s = v[k] >= 1.0;
            r[k] = s ? 1.0f : 0.0f;
            v[k] = s ? 0.0 : v[k];
        }
        float4 o = make_float4(r[0], r[1], r[2], r[3]);
        *reinterpret_cast<float4*>(obase + t * (NC * NL)) = o;
    }
}

extern "C" void kernel_launch(void* const* d_in, const int* in_sizes, int n_in,
                              void* d_out, int out_size, void* d_ws, size_t ws_size,
                              hipStream_t stream) {
    const float* inputs = (const float*)d_in[0];   // [B, L, C]
    const float* gamma  = (const float*)d_in[1];   // [1]
    const float* beta   = (const float*)d_in[2];   // [1]
    const float* enc_w  = (const float*)d_in[3];   // [T, 1]
    const float* enc_b  = (const float*)d_in[4];   // [T]
    float* out = (float*)d_out;                    // [B, T, C, L]

    double* part = (double*)d_ws;                  // 512 doubles (256 blocks x 2)
    double* coef = part + 512;                     // 2 doubles {A, Bc}

    reduce_kernel  <<<256, 256, 0, stream>>>(inputs, part);
    finalize_kernel<<<1,   256, 0, stream>>>(part, gamma, beta, coef);
    lif_kernel     <<<1024, 256, 0, stream>>>(inputs, enc_w, enc_b, coef, out);
}